// Round 2
// baseline (1890.677 us; speedup 1.0000x reference)
//
#include <hip/hip_runtime.h>

#define VOCAB  50257
#define VPAD   50304          // 64*786 padded vocab
#define SLEN   786            // vocab per slice (64 slices)
#define SDEC   63             // decode steps (S_TGT-1)

struct Params {
  const int   *xsrc, *xtgt;
  const float *eemb, *eWih0, *eWhh0, *ebih0, *ebhh0, *eWih1, *eWhh1, *ebih1, *ebhh1;
  const float *demb, *dWih0, *dWhh0, *dbih0, *dbhh0, *dWih1, *dWhh1, *dbih1, *dbhh1;
  const float *fcW, *fcb;
  float *out;
  unsigned long long *win;   // [SDEC*32] packed argmax winners
  float *Sh0, *Sc0, *Sh1, *Sc1;  // [32*32] decoder states
  float4 *cw;                // [4*8*128] transposed decoder cell weights
  float4 *fcp;               // [8*VPAD] transposed fc_W
  int use_pack;
};

__device__ __forceinline__ float sigm(float x) { return 1.f / (1.f + expf(-x)); }
__device__ __forceinline__ float dot4(float4 a, float4 b) {
  return a.x * b.x + a.y * b.y + a.z * b.z + a.w * b.w;
}

// ---------------- prep: encoder (blocks 0..31) + ws init/packing ----------------
__global__ __launch_bounds__(256) void prep_kernel(Params p)
{
  const int tid = threadIdx.x, blk = blockIdx.x;
  __shared__ __align__(16) float sH0[32], sC0[32], sH1[32], sC1[32], sG[128];

  if (blk < 32) {
    // encoder for batch row `blk`; thread tid<128 owns gate `tid` of both layers
    float4 wi0[8], wh0[8], wi1[8], wh1[8];
    float bs0 = 0.f, bs1 = 0.f;
    if (tid < 128) {
      const float4* a0 = (const float4*)(p.eWih0 + tid * 32);
      const float4* b0 = (const float4*)(p.eWhh0 + tid * 32);
      const float4* a1 = (const float4*)(p.eWih1 + tid * 32);
      const float4* b1 = (const float4*)(p.eWhh1 + tid * 32);
#pragma unroll
      for (int c = 0; c < 8; ++c) { wi0[c] = a0[c]; wh0[c] = b0[c]; wi1[c] = a1[c]; wh1[c] = b1[c]; }
      bs0 = p.ebih0[tid] + p.ebhh0[tid];
      bs1 = p.ebih1[tid] + p.ebhh1[tid];
    }
    if (tid < 32) { sH0[tid] = 0.f; sC0[tid] = 0.f; sH1[tid] = 0.f; sC1[tid] = 0.f; }
    __syncthreads();
    for (int t = 0; t < 64; ++t) {
      const int tok = p.xsrc[t * 32 + blk];
      if (tid < 128) {
        const float4* xe = (const float4*)(p.eemb + (size_t)tok * 32);
        const float4* h4 = (const float4*)sH0;
        float a = bs0;
#pragma unroll
        for (int c = 0; c < 8; ++c) a += dot4(wi0[c], xe[c]);
#pragma unroll
        for (int c = 0; c < 8; ++c) a += dot4(wh0[c], h4[c]);
        sG[tid] = a;
      }
      __syncthreads();
      if (tid < 32) {
        float gi = sigm(sG[tid]), gf = sigm(sG[32 + tid]);
        float gg = tanhf(sG[64 + tid]), go = sigm(sG[96 + tid]);
        float c = gf * sC0[tid] + gi * gg;
        sC0[tid] = c; sH0[tid] = go * tanhf(c);
      }
      __syncthreads();
      if (tid < 128) {
        const float4* x4 = (const float4*)sH0;   // new h0 = layer1 input
        const float4* h4 = (const float4*)sH1;
        float a = bs1;
#pragma unroll
        for (int c = 0; c < 8; ++c) a += dot4(wi1[c], x4[c]);
#pragma unroll
        for (int c = 0; c < 8; ++c) a += dot4(wh1[c], h4[c]);
        sG[tid] = a;
      }
      __syncthreads();
      if (tid < 32) {
        float gi = sigm(sG[tid]), gf = sigm(sG[32 + tid]);
        float gg = tanhf(sG[64 + tid]), go = sigm(sG[96 + tid]);
        float c = gf * sC1[tid] + gi * gg;
        sC1[tid] = c; sH1[tid] = go * tanhf(c);
      }
      __syncthreads();
    }
    if (tid < 32) {   // decoder initial state = encoder finals
      p.Sh0[blk * 32 + tid] = sH0[tid];
      p.Sc0[blk * 32 + tid] = sC0[tid];
      p.Sh1[blk * 32 + tid] = sH1[tid];
      p.Sc1[blk * 32 + tid] = sC1[tid];
    }
  } else if (blk == 32) {
    for (int i = tid; i < SDEC * 32; i += 256) p.win[i] = 0ull;
  } else if (p.use_pack) {
    if (blk == 33) {
      // transpose decoder cell weights: [mat][g][jo] -> [mat][jo][g] float4
      for (int i = tid; i < 4 * 8 * 128; i += 256) {
        const int mat = i >> 10, rem = i & 1023, jo = rem >> 7, g = rem & 127;
        const float* W = (mat == 0) ? p.dWih0 : (mat == 1) ? p.dWhh0
                       : (mat == 2) ? p.dWih1 : p.dWhh1;
        const float* s = W + g * 32 + jo * 4;
        p.cw[i] = make_float4(s[0], s[1], s[2], s[3]);
      }
    } else {
      // transpose fc_W: [v][c] -> [c][v] float4 (lane-coalesced vocab reads)
      const int gid = (blk - 34) * 256 + tid, stride = (256 - 34) * 256;
      for (int v = gid; v < VOCAB; v += stride) {
        const float4* s = (const float4*)(p.fcW + (size_t)v * 32);
#pragma unroll
        for (int c = 0; c < 8; ++c) p.fcp[(size_t)c * VPAD + v] = s[c];
      }
    }
  }
}

// ---------------- per-step decoder cell: 32 blocks (one per batch row) ----------------
__global__ __launch_bounds__(128) void cell_kernel(Params p, int t)
{
  const int tid = threadIdx.x, row = blockIdx.x;
  __shared__ __align__(16) float sH0[32], sH1[32], sC0[32], sC1[32], sX[32], sG[128];

  if (tid < 32) {
    sH0[tid] = p.Sh0[row * 32 + tid];
    sC0[tid] = p.Sc0[row * 32 + tid];
    sH1[tid] = p.Sh1[row * 32 + tid];
    sC1[tid] = p.Sc1[row * 32 + tid];
  }
  __shared__ int sTok;
  if (tid == 0) {
    int tok;
    if (t == 0) tok = p.xtgt[row];
    else {
      unsigned long long w = __hip_atomic_load(&p.win[(t - 1) * 32 + row],
                                               __ATOMIC_RELAXED, __HIP_MEMORY_SCOPE_AGENT);
      tok = (int)(~(unsigned)w);
    }
    sTok = tok;
  }
  __syncthreads();
  if (tid < 8) ((float4*)sX)[tid] = ((const float4*)(p.demb + (size_t)sTok * 32))[tid];
  __syncthreads();

  const int wstep = p.use_pack ? 128 : 1;
  { // layer 0
    const float4* xe = (const float4*)sX;
    const float4* h4 = (const float4*)sH0;
    const float4* wi = p.use_pack ? (p.cw + tid)        : ((const float4*)p.dWih0 + tid * 8);
    const float4* wh = p.use_pack ? (p.cw + 1024 + tid) : ((const float4*)p.dWhh0 + tid * 8);
    float a = p.dbih0[tid] + p.dbhh0[tid];
#pragma unroll
    for (int jo = 0; jo < 8; ++jo) a += dot4(wi[jo * wstep], xe[jo]);
#pragma unroll
    for (int jo = 0; jo < 8; ++jo) a += dot4(wh[jo * wstep], h4[jo]);
    sG[tid] = a;
  }
  __syncthreads();
  if (tid < 32) {
    float gi = sigm(sG[tid]), gf = sigm(sG[32 + tid]);
    float gg = tanhf(sG[64 + tid]), go = sigm(sG[96 + tid]);
    float c = gf * sC0[tid] + gi * gg;
    sC0[tid] = c; sH0[tid] = go * tanhf(c);
  }
  __syncthreads();
  { // layer 1 (input = new h0)
    const float4* xe = (const float4*)sH0;
    const float4* h4 = (const float4*)sH1;
    const float4* wi = p.use_pack ? (p.cw + 2048 + tid) : ((const float4*)p.dWih1 + tid * 8);
    const float4* wh = p.use_pack ? (p.cw + 3072 + tid) : ((const float4*)p.dWhh1 + tid * 8);
    float a = p.dbih1[tid] + p.dbhh1[tid];
#pragma unroll
    for (int jo = 0; jo < 8; ++jo) a += dot4(wi[jo * wstep], xe[jo]);
#pragma unroll
    for (int jo = 0; jo < 8; ++jo) a += dot4(wh[jo * wstep], h4[jo]);
    sG[tid] = a;
  }
  __syncthreads();
  if (tid < 32) {
    float gi = sigm(sG[tid]), gf = sigm(sG[32 + tid]);
    float gg = tanhf(sG[64 + tid]), go = sigm(sG[96 + tid]);
    float c = gf * sC1[tid] + gi * gg;
    float h = go * tanhf(c);
    p.Sh0[row * 32 + tid] = sH0[tid];
    p.Sc0[row * 32 + tid] = sC0[tid];
    p.Sh1[row * 32 + tid] = h;
    p.Sc1[row * 32 + tid] = c;
  }
}

// ---------------- per-step logits + argmax: 512 blocks x 256 threads ----------------
// slice = blk & 63 (same-slice blocks share an XCD under round-robin %8 mapping),
// grp = blk >> 6 in [0,8): rows grp*4 .. grp*4+3.
__global__ __launch_bounds__(256) void logits_kernel(Params p, int t)
{
  const int tid = threadIdx.x;
  const int slice = blockIdx.x & 63, grp = blockIdx.x >> 6;
  const int v0 = slice * SLEN, v1 = min(VOCAB, v0 + SLEN);
  __shared__ unsigned long long redw[4][4];

  float4 hr[4][8];                 // 4 rows x 32 h-values in VGPRs
  {
    const float4* hb = (const float4*)p.Sh1;
#pragma unroll
    for (int r = 0; r < 4; ++r) {
      const int row = grp * 4 + r;
#pragma unroll
      for (int c = 0; c < 8; ++c) hr[r][c] = hb[row * 8 + c];
    }
  }
  unsigned long long best[4] = {0ull, 0ull, 0ull, 0ull};
  const size_t ob = ((size_t)t * 32 + grp * 4) * VOCAB;

  for (int v = v0 + tid; v < v1; v += 256) {
    float4 w0, w1, w2, w3, w4, w5, w6, w7;
    if (p.use_pack) {
      w0 = p.fcp[v];              w1 = p.fcp[VPAD + v];
      w2 = p.fcp[2 * VPAD + v];   w3 = p.fcp[3 * VPAD + v];
      w4 = p.fcp[4 * VPAD + v];   w5 = p.fcp[5 * VPAD + v];
      w6 = p.fcp[6 * VPAD + v];   w7 = p.fcp[7 * VPAD + v];
    } else {
      const float4* wp = (const float4*)(p.fcW + (size_t)v * 32);
      w0 = wp[0]; w1 = wp[1]; w2 = wp[2]; w3 = wp[3];
      w4 = wp[4]; w5 = wp[5]; w6 = wp[6]; w7 = wp[7];
    }
    const float bb = p.fcb[v];
#pragma unroll
    for (int r = 0; r < 4; ++r) {
      float a = bb
        + dot4(hr[r][0], w0) + dot4(hr[r][1], w1) + dot4(hr[r][2], w2) + dot4(hr[r][3], w3)
        + dot4(hr[r][4], w4) + dot4(hr[r][5], w5) + dot4(hr[r][6], w6) + dot4(hr[r][7], w7);
      p.out[ob + (size_t)r * VOCAB + v] = a;
      unsigned ui = __float_as_uint(a);
      ui = (ui & 0x80000000u) ? ~ui : (ui | 0x80000000u);   // monotone float->uint
      unsigned long long pk = ((unsigned long long)ui << 32) | (unsigned)(~(unsigned)v);
      if (pk > best[r]) best[r] = pk;   // ties -> smallest v (matches jnp.argmax)
    }
  }

  // wave shuffle-reduce (64 lanes), then 4 waves via LDS, then atomicMax per row
#pragma unroll
  for (int off = 32; off > 0; off >>= 1) {
#pragma unroll
    for (int r = 0; r < 4; ++r) {
      unsigned long long o = __shfl_down(best[r], (unsigned)off, 64);
      if (o > best[r]) best[r] = o;
    }
  }
  if ((tid & 63) == 0) {
    const int wv = tid >> 6;
#pragma unroll
    for (int r = 0; r < 4; ++r) redw[wv][r] = best[r];
  }
  __syncthreads();
  if (tid < 4) {
    unsigned long long m = redw[0][tid];
    if (redw[1][tid] > m) m = redw[1][tid];
    if (redw[2][tid] > m) m = redw[2][tid];
    if (redw[3][tid] > m) m = redw[3][tid];
    atomicMax(&p.win[t * 32 + grp * 4 + tid], m);
  }
}

extern "C" void kernel_launch(void* const* d_in, const int* in_sizes, int n_in,
                              void* d_out, int out_size, void* d_ws, size_t ws_size,
                              hipStream_t stream) {
  Params p;
  p.xsrc  = (const int*)d_in[0];
  p.xtgt  = (const int*)d_in[1];
  p.eemb  = (const float*)d_in[2];
  p.eWih0 = (const float*)d_in[3];
  p.eWhh0 = (const float*)d_in[4];
  p.ebih0 = (const float*)d_in[5];
  p.ebhh0 = (const float*)d_in[6];
  p.eWih1 = (const float*)d_in[7];
  p.eWhh1 = (const float*)d_in[8];
  p.ebih1 = (const float*)d_in[9];
  p.ebhh1 = (const float*)d_in[10];
  p.demb  = (const float*)d_in[11];
  p.dWih0 = (const float*)d_in[12];
  p.dWhh0 = (const float*)d_in[13];
  p.dbih0 = (const float*)d_in[14];
  p.dbhh0 = (const float*)d_in[15];
  p.dWih1 = (const float*)d_in[16];
  p.dWhh1 = (const float*)d_in[17];
  p.dbih1 = (const float*)d_in[18];
  p.dbhh1 = (const float*)d_in[19];
  p.fcW   = (const float*)d_in[20];
  p.fcb   = (const float*)d_in[21];
  p.out   = (float*)d_out;

  char* ws = (char*)d_ws;
  p.win = (unsigned long long*)(ws);           // 16384 B (need 16128)
  p.Sh0 = (float*)(ws + 16384);                // 4 KB each
  p.Sc0 = (float*)(ws + 20480);
  p.Sh1 = (float*)(ws + 24576);
  p.Sc1 = (float*)(ws + 28672);
  p.cw  = (float4*)(ws + 32768);               // 65536 B
  p.fcp = (float4*)(ws + 98304);               // 8*VPAD*16 = 6438912 B
  const size_t need = 98304 + (size_t)8 * VPAD * 16;
  p.use_pack = (ws_size >= need) ? 1 : 0;      // fallback: row-major direct reads

  prep_kernel<<<dim3(256), dim3(256), 0, stream>>>(p);
  for (int t = 0; t < SDEC; ++t) {
    cell_kernel<<<dim3(32), dim3(128), 0, stream>>>(p, t);
    logits_kernel<<<dim3(512), dim3(256), 0, stream>>>(p, t);
  }
}